// Round 3
// baseline (593.567 us; speedup 1.0000x reference)
//
#include <hip/hip_runtime.h>
#include <hip/hip_bf16.h>

typedef __bf16 bf16;
typedef __attribute__((ext_vector_type(8))) __bf16 bf16x8;
typedef __attribute__((ext_vector_type(4))) float f32x4;

static_assert(sizeof(bf16x8) == 16, "bf16x8 must be 16B");

constexpr int N_NODES = 10000;
constexpr int N_EDGES = 320000;
constexpr int KPAD    = 264;   // LDS row stride (bf16): 528B/row -> 2-way bank aliasing (free per m136)

__device__ __forceinline__ float silu_f(float x) { return x / (1.0f + __expf(-x)); }

// ---- wave-level 64x64 MFMA GEMM, K=256, A in LDS [64 x KPAD], BT global (row n, contiguous k)
__device__ __forceinline__ void mfma_64x64_k256(const bf16* A, const bf16* BT, int b_stride,
                                                int r, int q, f32x4 acc[4][4]) {
  for (int k0 = 0; k0 < 256; k0 += 32) {
    bf16x8 a[4], b[4];
#pragma unroll
    for (int mi = 0; mi < 4; ++mi)
      a[mi] = *(const bf16x8*)(A + (16 * mi + r) * KPAD + k0 + q * 8);
#pragma unroll
    for (int ni = 0; ni < 4; ++ni)
      b[ni] = *(const bf16x8*)(BT + (size_t)(16 * ni + r) * b_stride + k0 + q * 8);
#pragma unroll
    for (int mi = 0; mi < 4; ++mi)
#pragma unroll
      for (int ni = 0; ni < 4; ++ni)
        acc[mi][ni] = __builtin_amdgcn_mfma_f32_16x16x32_bf16(a[mi], b[ni], acc[mi][ni], 0, 0, 0);
  }
}

// ---- prep: h -> bf16; transpose+convert weights to bf16 [n][k]
__global__ __launch_bounds__(256) void prep_kernel(
    const float* __restrict__ h, const float* __restrict__ We1, const float* __restrict__ We2,
    const float* __restrict__ Wn1, const float* __restrict__ Wn2, const float* __restrict__ Wc1,
    bf16* __restrict__ Hb, bf16* __restrict__ We1T, bf16* __restrict__ Wn1T,
    bf16* __restrict__ We2T, bf16* __restrict__ Wn2T, bf16* __restrict__ Wc1T) {
  int bid = blockIdx.x, tid = threadIdx.x;
  if (bid < 10000) { int i = bid * 256 + tid; Hb[i] = (bf16)h[i]; return; }
  int t = (bid - 10000) * 256 + tid;
  if (t < 131072) { int k = t >> 8, j = t & 255; We1T[j * 512 + k] = (bf16)We1[k * 256 + j]; return; }
  t -= 131072;
  if (t < 131072) { int k = t >> 8, j = t & 255; Wn1T[j * 512 + k] = (bf16)Wn1[k * 256 + j]; return; }
  t -= 131072;
  if (t < 65536) { int k = t >> 8, j = t & 255; We2T[j * 256 + k] = (bf16)We2[k * 256 + j]; return; }
  t -= 65536;
  if (t < 65536) { int k = t >> 8, j = t & 255; Wn2T[j * 256 + k] = (bf16)Wn2[k * 256 + j]; return; }
  t -= 65536;
  if (t < 65536) { int k = t >> 8, j = t & 255; Wc1T[j * 256 + k] = (bf16)Wc1[k * 256 + j]; return; }
}

// ---- counting sort of edges by row: hist -> scan -> scatter
__global__ __launch_bounds__(256) void hist_kernel(const int* __restrict__ eidx, int* __restrict__ hist) {
  int e = blockIdx.x * 256 + threadIdx.x;
  if (e < N_EDGES) atomicAdd(&hist[eidx[e]], 1);
}

__global__ __launch_bounds__(256) void scan_kernel(const int* __restrict__ hist,
                                                   int* __restrict__ base, int* __restrict__ cursor) {
  __shared__ int partial[256];
  int t = threadIdx.x;
  int s = 0;
#pragma unroll 4
  for (int i = 0; i < 40; ++i) { int idx = t * 40 + i; if (idx < N_NODES) s += hist[idx]; }
  partial[t] = s;
  __syncthreads();
  if (t == 0) { int run = 0; for (int i = 0; i < 256; ++i) { int v = partial[i]; partial[i] = run; run += v; } }
  __syncthreads();
  int run = partial[t];
  for (int i = 0; i < 40; ++i) {
    int idx = t * 40 + i;
    if (idx < N_NODES) { base[idx] = run; cursor[idx] = run; run += hist[idx]; }
  }
}

__global__ __launch_bounds__(256) void scatter_kernel(const int* __restrict__ eidx, int* __restrict__ cursor,
                                                      int* __restrict__ rs, int* __restrict__ cs) {
  int e = blockIdx.x * 256 + threadIdx.x;
  if (e < N_EDGES) {
    int r = eidx[e], c = eidx[N_EDGES + e];
    int p = atomicAdd(&cursor[r], 1);
    rs[p] = r; cs[p] = c;
  }
}

// ---- P/Q GEMM writing f32 (big path). P gets be1 folded in.
__global__ __launch_bounds__(256, 2) void gemm_pq_f32(const bf16* __restrict__ Hb,
                                                      const bf16* __restrict__ We1T,
                                                      const float* __restrict__ be1,
                                                      float* __restrict__ Pf, float* __restrict__ Qf) {
  int tid = threadIdx.x, w = tid >> 6, lane = tid & 63, r = lane & 15, q = lane >> 4;
  int m0 = blockIdx.x * 64;
  const bf16* BT = We1T + (blockIdx.y ? 256 : 0) + (size_t)(w * 64) * 512;
  float* OUT = blockIdx.y ? Qf : Pf;
  bool addb = (blockIdx.y == 0);
  f32x4 acc[4][4];
#pragma unroll
  for (int mi = 0; mi < 4; ++mi)
#pragma unroll
    for (int ni = 0; ni < 4; ++ni) acc[mi][ni] = (f32x4){0.f, 0.f, 0.f, 0.f};

  for (int k0 = 0; k0 < 256; k0 += 32) {
    bf16x8 a[4], b[4];
#pragma unroll
    for (int mi = 0; mi < 4; ++mi) {
      int m = m0 + 16 * mi + r; if (m > N_NODES - 1) m = N_NODES - 1;
      a[mi] = *(const bf16x8*)(Hb + (size_t)m * 256 + k0 + q * 8);
    }
#pragma unroll
    for (int ni = 0; ni < 4; ++ni)
      b[ni] = *(const bf16x8*)(BT + (size_t)(16 * ni + r) * 512 + k0 + q * 8);
#pragma unroll
    for (int mi = 0; mi < 4; ++mi)
#pragma unroll
      for (int ni = 0; ni < 4; ++ni)
        acc[mi][ni] = __builtin_amdgcn_mfma_f32_16x16x32_bf16(a[mi], b[ni], acc[mi][ni], 0, 0, 0);
  }
#pragma unroll
  for (int ni = 0; ni < 4; ++ni) {
    int n = w * 64 + 16 * ni + (lane & 15);
    float bv = addb ? be1[n] : 0.f;
#pragma unroll
    for (int mi = 0; mi < 4; ++mi)
#pragma unroll
      for (int rg = 0; rg < 4; ++rg) {
        int m = m0 + 16 * mi + q * 4 + rg;
        if (m < N_NODES) OUT[(size_t)m * 256 + n] = acc[mi][ni][rg] + bv;
      }
  }
}

// ---- (big path) phase-1 edge kernel: GEMM chain, stream ef + trans to global, no atomics
__global__ __launch_bounds__(256, 4) void edge_store_kernel(
    const float* __restrict__ coord, const int* __restrict__ rs, const int* __restrict__ cs,
    const float* __restrict__ We1, const float* __restrict__ be2, const float* __restrict__ bc1,
    const float* __restrict__ Wc2, const float* __restrict__ bc2,
    const float* __restrict__ Pf, const float* __restrict__ Qf,
    const bf16* __restrict__ We2T, const bf16* __restrict__ Wc1T,
    bf16* __restrict__ ef, float* __restrict__ trans) {
  __shared__ __align__(16) bf16 buf[64 * KPAD];
  __shared__ int s_row[64], s_col[64];
  __shared__ float s_rad[64], s_cd[64][3], s_part[64][4];

  int tid = threadIdx.x;
  int e0 = blockIdx.x * 64;
  int w = tid >> 6, lane = tid & 63, r = lane & 15, q = lane >> 4;

  if (tid < 64) {
    int e = e0 + tid;
    int ri = rs[e], ci = cs[e];
    s_row[tid] = ri; s_col[tid] = ci;
    float dx = coord[3 * ri + 0] - coord[3 * ci + 0];
    float dy = coord[3 * ri + 1] - coord[3 * ci + 1];
    float dz = coord[3 * ri + 2] - coord[3 * ci + 2];
    s_cd[tid][0] = dx; s_cd[tid][1] = dy; s_cd[tid][2] = dz;
    s_rad[tid] = dx * dx + dy * dy + dz * dz;
  }
  __syncthreads();

  // e1 = silu(P[row] + Q[col] + radial*We1[512]) -> buf (bias be1 pre-folded into P)
  {
    int off = (tid & 31) * 8;
    int esub = tid >> 5;
    float wv[8];
#pragma unroll
    for (int j = 0; j < 8; ++j) wv[j] = We1[512 * 256 + off + j];
#pragma unroll
    for (int p = 0; p < 8; ++p) {
      int e = p * 8 + esub;
      int ri = s_row[e], ci = s_col[e];
      const float* pp = Pf + (size_t)ri * 256 + off;
      const float* qq = Qf + (size_t)ci * 256 + off;
      float4 a0 = *(const float4*)pp, a1 = *(const float4*)(pp + 4);
      float4 b0 = *(const float4*)qq, b1 = *(const float4*)(qq + 4);
      float rad = s_rad[e];
      bf16x8 o;
      o[0] = (bf16)silu_f(a0.x + b0.x + rad * wv[0]);
      o[1] = (bf16)silu_f(a0.y + b0.y + rad * wv[1]);
      o[2] = (bf16)silu_f(a0.z + b0.z + rad * wv[2]);
      o[3] = (bf16)silu_f(a0.w + b0.w + rad * wv[3]);
      o[4] = (bf16)silu_f(a1.x + b1.x + rad * wv[4]);
      o[5] = (bf16)silu_f(a1.y + b1.y + rad * wv[5]);
      o[6] = (bf16)silu_f(a1.z + b1.z + rad * wv[6]);
      o[7] = (bf16)silu_f(a1.w + b1.w + rad * wv[7]);
      *(bf16x8*)(buf + e * KPAD + off) = o;
    }
  }
  __syncthreads();

  // GEMM1: edge_feat = silu(e1 @ We2 + be2) -> buf
  {
    f32x4 acc[4][4];
#pragma unroll
    for (int mi = 0; mi < 4; ++mi)
#pragma unroll
      for (int ni = 0; ni < 4; ++ni) acc[mi][ni] = (f32x4){0.f, 0.f, 0.f, 0.f};
    mfma_64x64_k256(buf, We2T + (size_t)(w * 64) * 256, 256, r, q, acc);
    __syncthreads();
#pragma unroll
    for (int ni = 0; ni < 4; ++ni) {
      int n = w * 64 + 16 * ni + r;
      float bv = be2[n];
#pragma unroll
      for (int mi = 0; mi < 4; ++mi)
#pragma unroll
        for (int rg = 0; rg < 4; ++rg) {
          int m = 16 * mi + q * 4 + rg;
          buf[m * KPAD + n] = (bf16)silu_f(acc[mi][ni][rg] + bv);
        }
    }
  }
  __syncthreads();

  // stream ef to global (coalesced-ish b128), issued before GEMM2 so stores overlap MFMA
  {
    int row = tid >> 2, c0 = (tid & 3) * 64;
#pragma unroll
    for (int k = 0; k < 64; k += 8) {
      bf16x8 v = *(const bf16x8*)(buf + row * KPAD + c0 + k);
      *(bf16x8*)(ef + (size_t)(e0 + row) * 256 + c0 + k) = v;
    }
  }

  // GEMM2: c1 = silu(edge_feat @ Wc1 + bc1) -> buf
  {
    f32x4 acc[4][4];
#pragma unroll
    for (int mi = 0; mi < 4; ++mi)
#pragma unroll
      for (int ni = 0; ni < 4; ++ni) acc[mi][ni] = (f32x4){0.f, 0.f, 0.f, 0.f};
    mfma_64x64_k256(buf, Wc1T + (size_t)(w * 64) * 256, 256, r, q, acc);
    __syncthreads();
#pragma unroll
    for (int ni = 0; ni < 4; ++ni) {
      int n = w * 64 + 16 * ni + r;
      float bv = bc1[n];
#pragma unroll
      for (int mi = 0; mi < 4; ++mi)
#pragma unroll
        for (int rg = 0; rg < 4; ++rg) {
          int m = 16 * mi + q * 4 + rg;
          buf[m * KPAD + n] = (bf16)silu_f(acc[mi][ni][rg] + bv);
        }
    }
  }
  __syncthreads();

  // scalar = c1 @ Wc2 + bc2 ; trans = coord_diff * scalar -> global
  {
    int e = tid >> 2, p = tid & 3;
    float s = 0.f;
#pragma unroll
    for (int kk = 0; kk < 64; kk += 8) {
      bf16x8 v = *(const bf16x8*)(buf + e * KPAD + p * 64 + kk);
#pragma unroll
      for (int j = 0; j < 8; ++j) s += (float)v[j] * Wc2[p * 64 + kk + j];
    }
    s_part[e][p] = s;
  }
  __syncthreads();
  if (tid < 64) {
    float s = s_part[tid][0] + s_part[tid][1] + s_part[tid][2] + s_part[tid][3] + bc2[0];
    size_t t3 = (size_t)(e0 + tid) * 3;
    trans[t3 + 0] = s_cd[tid][0] * s;
    trans[t3 + 1] = s_cd[tid][1] * s;
    trans[t3 + 2] = s_cd[tid][2] * s;
  }
}

// ---- (big path) phase-2: CSR aggregation + coord_out + fused node MLP
__global__ __launch_bounds__(256, 2) void agg_node_kernel(
    const bf16* __restrict__ Hb, const bf16* __restrict__ ef, const float* __restrict__ trans,
    const int* __restrict__ base, const int* __restrict__ endp,
    const float* __restrict__ coord,
    const bf16* __restrict__ Wn1T, const bf16* __restrict__ Wn2T,
    const float* __restrict__ bn1, const float* __restrict__ bn2,
    float* __restrict__ h_out, float* __restrict__ coord_out) {
  __shared__ __align__(16) bf16 buf[64 * KPAD];  // aggb, then hidden
  int tid = threadIdx.x, w = tid >> 6, lane = tid & 63, r = lane & 15, q = lane >> 4;
  int m0 = blockIdx.x * 64;

  // aggregate ef rows per node (CSR contiguous, coalesced across 32-lane col groups)
  {
    int strip = tid >> 5;            // 0..7 -> 8 nodes each
    int off = (tid & 31) * 8;        // col octet
#pragma unroll
    for (int i = 0; i < 8; ++i) {
      int lm = strip * 8 + i;        // local row 0..63
      int m = m0 + lm;
      float acc[8] = {0, 0, 0, 0, 0, 0, 0, 0};
      if (m < N_NODES) {
        int b = base[m], e = endp[m];
        for (int p = b; p < e; ++p) {
          bf16x8 v = *(const bf16x8*)(ef + (size_t)p * 256 + off);
#pragma unroll
          for (int j = 0; j < 8; ++j) acc[j] += (float)v[j];
        }
      }
      bf16x8 o;
#pragma unroll
      for (int j = 0; j < 8; ++j) o[j] = (bf16)acc[j];
      *(bf16x8*)(buf + lm * KPAD + off) = o;
    }
  }
  // coord_out
  if (tid < 64) {
    int m = m0 + tid;
    if (m < N_NODES) {
      int b = base[m], e = endp[m];
      float sx = 0.f, sy = 0.f, sz = 0.f;
      for (int p = b; p < e; ++p) {
        sx += trans[3 * (size_t)p + 0];
        sy += trans[3 * (size_t)p + 1];
        sz += trans[3 * (size_t)p + 2];
      }
      float c = (float)(e - b); if (c < 1.f) c = 1.f;
      coord_out[3 * m + 0] = coord[3 * m + 0] + sx / c;
      coord_out[3 * m + 1] = coord[3 * m + 1] + sy / c;
      coord_out[3 * m + 2] = coord[3 * m + 2] + sz / c;
    }
  }
  __syncthreads();

  // node MLP layer1: [h | agg] @ Wn1 + bn1, silu
  f32x4 acc[4][4];
#pragma unroll
  for (int mi = 0; mi < 4; ++mi)
#pragma unroll
    for (int ni = 0; ni < 4; ++ni) acc[mi][ni] = (f32x4){0.f, 0.f, 0.f, 0.f};
  const bf16* BT1 = Wn1T + (size_t)(w * 64) * 512;
  for (int k0 = 0; k0 < 256; k0 += 32) {
    bf16x8 a[4], b[4];
#pragma unroll
    for (int mi = 0; mi < 4; ++mi) {
      int m = m0 + 16 * mi + r; if (m > N_NODES - 1) m = N_NODES - 1;
      a[mi] = *(const bf16x8*)(Hb + (size_t)m * 256 + k0 + q * 8);
    }
#pragma unroll
    for (int ni = 0; ni < 4; ++ni)
      b[ni] = *(const bf16x8*)(BT1 + (size_t)(16 * ni + r) * 512 + k0 + q * 8);
#pragma unroll
    for (int mi = 0; mi < 4; ++mi)
#pragma unroll
      for (int ni = 0; ni < 4; ++ni)
        acc[mi][ni] = __builtin_amdgcn_mfma_f32_16x16x32_bf16(a[mi], b[ni], acc[mi][ni], 0, 0, 0);
  }
  for (int k0 = 0; k0 < 256; k0 += 32) {
    bf16x8 a[4], b[4];
#pragma unroll
    for (int mi = 0; mi < 4; ++mi)
      a[mi] = *(const bf16x8*)(buf + (16 * mi + r) * KPAD + k0 + q * 8);
#pragma unroll
    for (int ni = 0; ni < 4; ++ni)
      b[ni] = *(const bf16x8*)(BT1 + (size_t)(16 * ni + r) * 512 + 256 + k0 + q * 8);
#pragma unroll
    for (int mi = 0; mi < 4; ++mi)
#pragma unroll
      for (int ni = 0; ni < 4; ++ni)
        acc[mi][ni] = __builtin_amdgcn_mfma_f32_16x16x32_bf16(a[mi], b[ni], acc[mi][ni], 0, 0, 0);
  }
  __syncthreads();
#pragma unroll
  for (int ni = 0; ni < 4; ++ni) {
    int n = w * 64 + 16 * ni + (lane & 15);
    float bv = bn1[n];
#pragma unroll
    for (int mi = 0; mi < 4; ++mi)
#pragma unroll
      for (int rg = 0; rg < 4; ++rg) {
        int m = 16 * mi + q * 4 + rg;
        buf[m * KPAD + n] = (bf16)silu_f(acc[mi][ni][rg] + bv);
      }
  }
  __syncthreads();
  // layer2 -> h_out
#pragma unroll
  for (int mi = 0; mi < 4; ++mi)
#pragma unroll
    for (int ni = 0; ni < 4; ++ni) acc[mi][ni] = (f32x4){0.f, 0.f, 0.f, 0.f};
  mfma_64x64_k256(buf, Wn2T + (size_t)(w * 64) * 256, 256, r, q, acc);
#pragma unroll
  for (int ni = 0; ni < 4; ++ni) {
    int n = w * 64 + 16 * ni + (lane & 15);
    float bv = bn2[n];
#pragma unroll
    for (int mi = 0; mi < 4; ++mi)
#pragma unroll
      for (int rg = 0; rg < 4; ++rg) {
        int m = m0 + 16 * mi + q * 4 + rg;
        if (m < N_NODES) h_out[(size_t)m * 256 + n] = acc[mi][ni][rg] + bv;
      }
  }
}

// ============================ R2 fallback path ============================
__global__ __launch_bounds__(256, 2) void gemm_pq(const bf16* __restrict__ Hb,
                                                  const bf16* __restrict__ We1T,
                                                  bf16* __restrict__ P, bf16* __restrict__ Q) {
  int tid = threadIdx.x, w = tid >> 6, lane = tid & 63, r = lane & 15, q = lane >> 4;
  int m0 = blockIdx.x * 64;
  const bf16* BT = We1T + (blockIdx.y ? 256 : 0) + (size_t)(w * 64) * 512;
  bf16* OUT = blockIdx.y ? Q : P;
  f32x4 acc[4][4];
#pragma unroll
  for (int mi = 0; mi < 4; ++mi)
#pragma unroll
    for (int ni = 0; ni < 4; ++ni) acc[mi][ni] = (f32x4){0.f, 0.f, 0.f, 0.f};
  for (int k0 = 0; k0 < 256; k0 += 32) {
    bf16x8 a[4], b[4];
#pragma unroll
    for (int mi = 0; mi < 4; ++mi) {
      int m = m0 + 16 * mi + r; if (m > N_NODES - 1) m = N_NODES - 1;
      a[mi] = *(const bf16x8*)(Hb + (size_t)m * 256 + k0 + q * 8);
    }
#pragma unroll
    for (int ni = 0; ni < 4; ++ni)
      b[ni] = *(const bf16x8*)(BT + (size_t)(16 * ni + r) * 512 + k0 + q * 8);
#pragma unroll
    for (int mi = 0; mi < 4; ++mi)
#pragma unroll
      for (int ni = 0; ni < 4; ++ni)
        acc[mi][ni] = __builtin_amdgcn_mfma_f32_16x16x32_bf16(a[mi], b[ni], acc[mi][ni], 0, 0, 0);
  }
#pragma unroll
  for (int ni = 0; ni < 4; ++ni) {
    int n = w * 64 + 16 * ni + (lane & 15);
#pragma unroll
    for (int mi = 0; mi < 4; ++mi)
#pragma unroll
      for (int rg = 0; rg < 4; ++rg) {
        int m = m0 + 16 * mi + q * 4 + rg;
        if (m < N_NODES) OUT[(size_t)m * 256 + n] = (bf16)acc[mi][ni][rg];
      }
  }
}

__global__ __launch_bounds__(256, 4) void edge_kernel(
    const float* __restrict__ coord, const int* __restrict__ rs, const int* __restrict__ cs,
    const float* __restrict__ We1, const float* __restrict__ be1,
    const float* __restrict__ be2, const float* __restrict__ bc1,
    const float* __restrict__ Wc2, const float* __restrict__ bc2,
    const bf16* __restrict__ P, const bf16* __restrict__ Q,
    const bf16* __restrict__ We2T, const bf16* __restrict__ Wc1T,
    float* __restrict__ agg_h, float* __restrict__ agg_c) {
  __shared__ __align__(16) bf16 buf[64 * KPAD];
  __shared__ int s_row[64], s_col[64];
  __shared__ float s_rad[64], s_cd[64][3], s_part[64][4], s_scal[64];
  int tid = threadIdx.x;
  int e0 = blockIdx.x * 64;
  int w = tid >> 6, lane = tid & 63, r = lane & 15, q = lane >> 4;
  if (tid < 64) {
    int e = e0 + tid;
    int ri = rs[e], ci = cs[e];
    s_row[tid] = ri; s_col[tid] = ci;
    float dx = coord[3 * ri + 0] - coord[3 * ci + 0];
    float dy = coord[3 * ri + 1] - coord[3 * ci + 1];
    float dz = coord[3 * ri + 2] - coord[3 * ci + 2];
    s_cd[tid][0] = dx; s_cd[tid][1] = dy; s_cd[tid][2] = dz;
    s_rad[tid] = dx * dx + dy * dy + dz * dz;
  }
  __syncthreads();
  {
    int off = (tid & 31) * 8;
    int esub = tid >> 5;
    float wv[8], bv[8];
#pragma unroll
    for (int j = 0; j < 8; ++j) { wv[j] = We1[512 * 256 + off + j]; bv[j] = be1[off + j]; }
#pragma unroll
    for (int p = 0; p < 8; ++p) {
      int e = p * 8 + esub;
      int ri = s_row[e], ci = s_col[e];
      bf16x8 pv = *(const bf16x8*)(P + (size_t)ri * 256 + off);
      bf16x8 qv = *(const bf16x8*)(Q + (size_t)ci * 256 + off);
      float rad = s_rad[e];
      bf16x8 o;
#pragma unroll
      for (int j = 0; j < 8; ++j)
        o[j] = (bf16)silu_f((float)pv[j] + (float)qv[j] + rad * wv[j] + bv[j]);
      *(bf16x8*)(buf + e * KPAD + off) = o;
    }
  }
  __syncthreads();
  {
    f32x4 acc[4][4];
#pragma unroll
    for (int mi = 0; mi < 4; ++mi)
#pragma unroll
      for (int ni = 0; ni < 4; ++ni) acc[mi][ni] = (f32x4){0.f, 0.f, 0.f, 0.f};
    mfma_64x64_k256(buf, We2T + (size_t)(w * 64) * 256, 256, r, q, acc);
    __syncthreads();
#pragma unroll
    for (int ni = 0; ni < 4; ++ni) {
      int n = w * 64 + 16 * ni + r;
      float bv = be2[n];
#pragma unroll
      for (int mi = 0; mi < 4; ++mi)
#pragma unroll
        for (int rg = 0; rg < 4; ++rg) {
          int m = 16 * mi + q * 4 + rg;
          buf[m * KPAD + n] = (bf16)silu_f(acc[mi][ni][rg] + bv);
        }
    }
  }
  __syncthreads();
  {
    float s = 0.f;
    int cur = s_row[0];
#pragma unroll 4
    for (int e = 0; e < 64; ++e) {
      int re = s_row[e];
      if (re != cur) { atomicAdd(&agg_h[(size_t)cur * 256 + tid], s); s = 0.f; cur = re; }
      s += (float)buf[e * KPAD + tid];
    }
    atomicAdd(&agg_h[(size_t)cur * 256 + tid], s);
  }
  {
    f32x4 acc[4][4];
#pragma unroll
    for (int mi = 0; mi < 4; ++mi)
#pragma unroll
      for (int ni = 0; ni < 4; ++ni) acc[mi][ni] = (f32x4){0.f, 0.f, 0.f, 0.f};
    mfma_64x64_k256(buf, Wc1T + (size_t)(w * 64) * 256, 256, r, q, acc);
    __syncthreads();
#pragma unroll
    for (int ni = 0; ni < 4; ++ni) {
      int n = w * 64 + 16 * ni + r;
      float bv = bc1[n];
#pragma unroll
      for (int mi = 0; mi < 4; ++mi)
#pragma unroll
        for (int rg = 0; rg < 4; ++rg) {
          int m = 16 * mi + q * 4 + rg;
          buf[m * KPAD + n] = (bf16)silu_f(acc[mi][ni][rg] + bv);
        }
    }
  }
  __syncthreads();
  {
    int e = tid >> 2, p = tid & 3;
    float s = 0.f;
#pragma unroll
    for (int kk = 0; kk < 64; kk += 8) {
      bf16x8 v = *(const bf16x8*)(buf + e * KPAD + p * 64 + kk);
#pragma unroll
      for (int j = 0; j < 8; ++j) s += (float)v[j] * Wc2[p * 64 + kk + j];
    }
    s_part[e][p] = s;
  }
  __syncthreads();
  if (tid < 64)
    s_scal[tid] = s_part[tid][0] + s_part[tid][1] + s_part[tid][2] + s_part[tid][3] + bc2[0];
  __syncthreads();
  if (tid < 3) {
    float s = 0.f;
    int cur = s_row[0];
    for (int e = 0; e < 64; ++e) {
      int re = s_row[e];
      if (re != cur) { atomicAdd(&agg_c[3 * cur + tid], s); s = 0.f; cur = re; }
      s += s_cd[e][tid] * s_scal[e];
    }
    atomicAdd(&agg_c[3 * cur + tid], s);
  }
}

__global__ __launch_bounds__(256) void post_kernel(
    const float* __restrict__ agg_h, bf16* __restrict__ Ab,
    const float* __restrict__ coord, const float* __restrict__ agg_c,
    const int* __restrict__ hist, float* __restrict__ coord_out) {
  int bid = blockIdx.x, tid = threadIdx.x;
  if (bid < 10000) { int i = bid * 256 + tid; Ab[i] = (bf16)agg_h[i]; return; }
  int t = (bid - 10000) * 256 + tid;
  if (t < 30000) {
    float c = (float)hist[t / 3]; if (c < 1.f) c = 1.f;
    coord_out[t] = coord[t] + agg_c[t] / c;
  }
}

__global__ __launch_bounds__(256, 2) void node_kernel(
    const bf16* __restrict__ Hb, const bf16* __restrict__ Ab,
    const bf16* __restrict__ Wn1T, const bf16* __restrict__ Wn2T,
    const float* __restrict__ bn1, const float* __restrict__ bn2,
    float* __restrict__ h_out) {
  __shared__ __align__(16) bf16 buf[64 * KPAD];
  int tid = threadIdx.x, w = tid >> 6, lane = tid & 63, r = lane & 15, q = lane >> 4;
  int m0 = blockIdx.x * 64;
  f32x4 acc[4][4];
#pragma unroll
  for (int mi = 0; mi < 4; ++mi)
#pragma unroll
    for (int ni = 0; ni < 4; ++ni) acc[mi][ni] = (f32x4){0.f, 0.f, 0.f, 0.f};
  const bf16* BT1 = Wn1T + (size_t)(w * 64) * 512;
  for (int k0 = 0; k0 < 256; k0 += 32) {
    bf16x8 a[4], b[4];
#pragma unroll
    for (int mi = 0; mi < 4; ++mi) {
      int m = m0 + 16 * mi + r; if (m > N_NODES - 1) m = N_NODES - 1;
      a[mi] = *(const bf16x8*)(Hb + (size_t)m * 256 + k0 + q * 8);
    }
#pragma unroll
    for (int ni = 0; ni < 4; ++ni)
      b[ni] = *(const bf16x8*)(BT1 + (size_t)(16 * ni + r) * 512 + k0 + q * 8);
#pragma unroll
    for (int mi = 0; mi < 4; ++mi)
#pragma unroll
      for (int ni = 0; ni < 4; ++ni)
        acc[mi][ni] = __builtin_amdgcn_mfma_f32_16x16x32_bf16(a[mi], b[ni], acc[mi][ni], 0, 0, 0);
  }
  for (int k0 = 0; k0 < 256; k0 += 32) {
    bf16x8 a[4], b[4];
#pragma unroll
    for (int mi = 0; mi < 4; ++mi) {
      int m = m0 + 16 * mi + r; if (m > N_NODES - 1) m = N_NODES - 1;
      a[mi] = *(const bf16x8*)(Ab + (size_t)m * 256 + k0 + q * 8);
    }
#pragma unroll
    for (int ni = 0; ni < 4; ++ni)
      b[ni] = *(const bf16x8*)(BT1 + (size_t)(16 * ni + r) * 512 + 256 + k0 + q * 8);
#pragma unroll
    for (int mi = 0; mi < 4; ++mi)
#pragma unroll
      for (int ni = 0; ni < 4; ++ni)
        acc[mi][ni] = __builtin_amdgcn_mfma_f32_16x16x32_bf16(a[mi], b[ni], acc[mi][ni], 0, 0, 0);
  }
#pragma unroll
  for (int ni = 0; ni < 4; ++ni) {
    int n = w * 64 + 16 * ni + (lane & 15);
    float bv = bn1[n];
#pragma unroll
    for (int mi = 0; mi < 4; ++mi)
#pragma unroll
      for (int rg = 0; rg < 4; ++rg) {
        int m = 16 * mi + q * 4 + rg;
        buf[m * KPAD + n] = (bf16)silu_f(acc[mi][ni][rg] + bv);
      }
  }
  __syncthreads();
#pragma unroll
  for (int mi = 0; mi < 4; ++mi)
#pragma unroll
    for (int ni = 0; ni < 4; ++ni) acc[mi][ni] = (f32x4){0.f, 0.f, 0.f, 0.f};
  mfma_64x64_k256(buf, Wn2T + (size_t)(w * 64) * 256, 256, r, q, acc);
#pragma unroll
  for (int ni = 0; ni < 4; ++ni) {
    int n = w * 64 + 16 * ni + (lane & 15);
    float bv = bn2[n];
#pragma unroll
    for (int mi = 0; mi < 4; ++mi)
#pragma unroll
      for (int rg = 0; rg < 4; ++rg) {
        int m = m0 + 16 * mi + q * 4 + rg;
        if (m < N_NODES) h_out[(size_t)m * 256 + n] = acc[mi][ni][rg] + bv;
      }
  }
}

extern "C" void kernel_launch(void* const* d_in, const int* in_sizes, int n_in,
                              void* d_out, int out_size, void* d_ws, size_t ws_size,
                              hipStream_t stream) {
  const float* h     = (const float*)d_in[0];
  const float* coord = (const float*)d_in[1];
  const int*   eidx  = (const int*)d_in[2];
  const float* We1 = (const float*)d_in[3];
  const float* be1 = (const float*)d_in[4];
  const float* We2 = (const float*)d_in[5];
  const float* be2 = (const float*)d_in[6];
  const float* Wn1 = (const float*)d_in[7];
  const float* bn1 = (const float*)d_in[8];
  const float* Wn2 = (const float*)d_in[9];
  const float* bn2 = (const float*)d_in[10];
  const float* Wc1 = (const float*)d_in[11];
  const float* bc1 = (const float*)d_in[12];
  const float* Wc2 = (const float*)d_in[13];
  const float* bc2 = (const float*)d_in[14];

  float* h_out = (float*)d_out;
  float* coord_out = h_out + (size_t)N_NODES * 256;
  char* ws = (char*)d_ws;

  if (ws_size >= 197000000ull) {
    // ---- big path: two-phase, no atomics in hot loop
    int*   hist  = (int*)  (ws + 0);           //     40,000
    int*   base  = (int*)  (ws + 40000);       //     40,000
    int*   cursor= (int*)  (ws + 80000);       //     40,000 (== end after scatter)
    int*   rs    = (int*)  (ws + 120000);      //  1,280,000
    int*   cs    = (int*)  (ws + 1400000);     //  1,280,000
    bf16*  Hb    = (bf16*) (ws + 2680000);     //  5,120,000
    float* Pf    = (float*)(ws + 7800000);     // 10,240,000
    float* Qf    = (float*)(ws + 18040000);    // 10,240,000
    bf16*  We1T  = (bf16*) (ws + 28280000);    //    262,144
    bf16*  Wn1T  = (bf16*) (ws + 28542144);    //    262,144
    bf16*  We2T  = (bf16*) (ws + 28804288);    //    131,072
    bf16*  Wn2T  = (bf16*) (ws + 28935360);    //    131,072
    bf16*  Wc1T  = (bf16*) (ws + 29066432);    //    131,072
    float* trans = (float*)(ws + 29197504);    //  3,840,000
    bf16*  ef    = (bf16*) (ws + 33037504);    // 163,840,000  -> end 196,877,504

    hipMemsetAsync(hist, 0, 40000, stream);
    prep_kernel<<<11792, 256, 0, stream>>>(h, We1, We2, Wn1, Wn2, Wc1,
                                           Hb, We1T, Wn1T, We2T, Wn2T, Wc1T);
    hist_kernel<<<1250, 256, 0, stream>>>(eidx, hist);
    scan_kernel<<<1, 256, 0, stream>>>(hist, base, cursor);
    scatter_kernel<<<1250, 256, 0, stream>>>(eidx, cursor, rs, cs);
    gemm_pq_f32<<<dim3(157, 2), 256, 0, stream>>>(Hb, We1T, be1, Pf, Qf);
    edge_store_kernel<<<5000, 256, 0, stream>>>(coord, rs, cs, We1, be2, bc1, Wc2, bc2,
                                                Pf, Qf, We2T, Wc1T, ef, trans);
    agg_node_kernel<<<157, 256, 0, stream>>>(Hb, ef, trans, base, cursor, coord,
                                             Wn1T, Wn2T, bn1, bn2, h_out, coord_out);
  } else {
    // ---- fallback: R2 path
    float* agg_h = (float*)(ws + 0);
    float* agg_c = (float*)(ws + 10240000);
    int*   hist  = (int*)  (ws + 10360000);
    int*   base  = (int*)  (ws + 10400000);
    int*   cursor= (int*)  (ws + 10440000);
    int*   rs    = (int*)  (ws + 10480000);
    int*   cs    = (int*)  (ws + 11760000);
    bf16* Hb   = (bf16*)(ws + 13040000);
    bf16* P    = (bf16*)(ws + 18160000);
    bf16* Q    = (bf16*)(ws + 23280000);
    bf16* Ab   = (bf16*)(ws + 28400000);
    bf16* We1T = (bf16*)(ws + 33520000);
    bf16* Wn1T = (bf16*)(ws + 33782144);
    bf16* We2T = (bf16*)(ws + 34044288);
    bf16* Wn2T = (bf16*)(ws + 34175360);
    bf16* Wc1T = (bf16*)(ws + 34306432);

    hipMemsetAsync(ws, 0, 10400000, stream);
    prep_kernel<<<11792, 256, 0, stream>>>(h, We1, We2, Wn1, Wn2, Wc1,
                                           Hb, We1T, Wn1T, We2T, Wn2T, Wc1T);
    hist_kernel<<<1250, 256, 0, stream>>>(eidx, hist);
    scan_kernel<<<1, 256, 0, stream>>>(hist, base, cursor);
    scatter_kernel<<<1250, 256, 0, stream>>>(eidx, cursor, rs, cs);
    gemm_pq<<<dim3(157, 2), 256, 0, stream>>>(Hb, We1T, P, Q);
    edge_kernel<<<5000, 256, 0, stream>>>(coord, rs, cs, We1, be1, be2, bc1, Wc2, bc2,
                                          P, Q, We2T, Wc1T, agg_h, agg_c);
    post_kernel<<<10118, 256, 0, stream>>>(agg_h, Ab, coord, agg_c, hist, coord_out);
    node_kernel<<<157, 256, 0, stream>>>(Hb, Ab, Wn1T, Wn2T, bn1, bn2, h_out);
  }
}

// Round 4
// 458.206 us; speedup vs baseline: 1.2954x; 1.2954x over previous
//
#include <hip/hip_runtime.h>
#include <hip/hip_bf16.h>

typedef __bf16 bf16;
typedef __attribute__((ext_vector_type(8))) __bf16 bf16x8;
typedef __attribute__((ext_vector_type(4))) float f32x4;

static_assert(sizeof(bf16x8) == 16, "bf16x8 must be 16B");

constexpr int N_NODES = 10000;
constexpr int N_EDGES = 320000;
constexpr int KPAD    = 264;   // LDS row stride (bf16): 528B/row -> 2-way bank aliasing (free per m136)

__device__ __forceinline__ float silu_f(float x) { return x / (1.0f + __expf(-x)); }

// pack two f32 -> (bf16(lo), bf16(hi)) in one u32; round-half-up via +0x8000 (<=1 ulp vs RNE)
__device__ __forceinline__ unsigned pk_bf16(float lo, float hi) {
  unsigned a = __float_as_uint(lo) + 0x8000u;
  unsigned b = __float_as_uint(hi) + 0x8000u;
  return __builtin_amdgcn_perm(b, a, 0x07060302u);  // bytes: [a.2,a.3,b.2,b.3]
}

// ---- transposed-output MFMA: acc[mi][ni] = WT-rows x edge-rows.
// D row(q*4+reg) = out channel (w*64+16*mi+4q+rg), D col(lane&15) = edge (16*ni+r).
__device__ __forceinline__ void mfmaT_k256(const bf16* __restrict__ WT, int wstride, int koff,
                                           const bf16* Albs, int w, int r, int q, f32x4 acc[4][4]) {
  for (int k0 = 0; k0 < 256; k0 += 32) {
    bf16x8 a[4], b[4];
#pragma unroll
    for (int mi = 0; mi < 4; ++mi)
      a[mi] = *(const bf16x8*)(WT + (size_t)(w * 64 + 16 * mi + r) * wstride + koff + k0 + q * 8);
#pragma unroll
    for (int ni = 0; ni < 4; ++ni)
      b[ni] = *(const bf16x8*)(Albs + (16 * ni + r) * KPAD + k0 + q * 8);
#pragma unroll
    for (int mi = 0; mi < 4; ++mi)
#pragma unroll
      for (int ni = 0; ni < 4; ++ni)
        acc[mi][ni] = __builtin_amdgcn_mfma_f32_16x16x32_bf16(a[mi], b[ni], acc[mi][ni], 0, 0, 0);
  }
}

// ---- prep (+fused hist): h -> bf16; weights -> bf16 transposed [n][k]; histogram of rows
__global__ __launch_bounds__(256) void prep_kernel(
    const float* __restrict__ h, const float* __restrict__ We1, const float* __restrict__ We2,
    const float* __restrict__ Wn1, const float* __restrict__ Wn2, const float* __restrict__ Wc1,
    const int* __restrict__ eidx,
    bf16* __restrict__ Hb, bf16* __restrict__ We1T, bf16* __restrict__ Wn1T,
    bf16* __restrict__ We2T, bf16* __restrict__ Wn2T, bf16* __restrict__ Wc1T,
    int* __restrict__ hist) {
  int bid = blockIdx.x, tid = threadIdx.x;
  if (bid < 10000) { int i = bid * 256 + tid; Hb[i] = (bf16)h[i]; return; }
  if (bid >= 11792) {
    int e = (bid - 11792) * 256 + tid;
    if (e < N_EDGES) atomicAdd(&hist[eidx[e]], 1);
    return;
  }
  int t = (bid - 10000) * 256 + tid;
  if (t < 131072) { int k = t >> 8, j = t & 255; We1T[j * 512 + k] = (bf16)We1[k * 256 + j]; return; }
  t -= 131072;
  if (t < 131072) { int k = t >> 8, j = t & 255; Wn1T[j * 512 + k] = (bf16)Wn1[k * 256 + j]; return; }
  t -= 131072;
  if (t < 65536) { int k = t >> 8, j = t & 255; We2T[j * 256 + k] = (bf16)We2[k * 256 + j]; return; }
  t -= 65536;
  if (t < 65536) { int k = t >> 8, j = t & 255; Wn2T[j * 256 + k] = (bf16)Wn2[k * 256 + j]; return; }
  t -= 65536;
  if (t < 65536) { int k = t >> 8, j = t & 255; Wc1T[j * 256 + k] = (bf16)Wc1[k * 256 + j]; return; }
}

// ---- scan (parallel Hillis-Steele over 256 partials)
__global__ __launch_bounds__(256) void scan_kernel(const int* __restrict__ hist,
                                                   int* __restrict__ base, int* __restrict__ cursor) {
  __shared__ int partial[256];
  int t = threadIdx.x;
  int s = 0;
  for (int i = 0; i < 40; ++i) { int idx = t * 40 + i; if (idx < N_NODES) s += hist[idx]; }
  partial[t] = s;
  __syncthreads();
  for (int d = 1; d < 256; d <<= 1) {
    int v = (t >= d) ? partial[t - d] : 0;
    __syncthreads();
    partial[t] += v;
    __syncthreads();
  }
  int run = partial[t] - s;  // exclusive
  for (int i = 0; i < 40; ++i) {
    int idx = t * 40 + i;
    if (idx < N_NODES) { base[idx] = run; cursor[idx] = run; run += hist[idx]; }
  }
}

__global__ __launch_bounds__(256) void scatter_kernel(const int* __restrict__ eidx, int* __restrict__ cursor,
                                                      int* __restrict__ rs, int* __restrict__ cs) {
  int e = blockIdx.x * 256 + threadIdx.x;
  if (e < N_EDGES) {
    int r = eidx[e], c = eidx[N_EDGES + e];
    int p = atomicAdd(&cursor[r], 1);
    rs[p] = r; cs[p] = c;
  }
}

// ---- P/Q GEMM (transposed-output, vectorized stores). P gets be1 folded in.
__global__ __launch_bounds__(256, 2) void gemm_pq(const bf16* __restrict__ Hb,
                                                  const bf16* __restrict__ We1T,
                                                  const float* __restrict__ be1,
                                                  bf16* __restrict__ P, bf16* __restrict__ Q) {
  int tid = threadIdx.x, w = tid >> 6, lane = tid & 63, r = lane & 15, q = lane >> 4;
  int m0 = blockIdx.x * 64;
  int koff = blockIdx.y ? 256 : 0;
  bf16* OUT = blockIdx.y ? Q : P;
  bool addb = (blockIdx.y == 0);
  f32x4 acc[4][4];
#pragma unroll
  for (int mi = 0; mi < 4; ++mi)
#pragma unroll
    for (int ni = 0; ni < 4; ++ni) acc[mi][ni] = (f32x4){0.f, 0.f, 0.f, 0.f};

  for (int k0 = 0; k0 < 256; k0 += 32) {
    bf16x8 a[4], b[4];
#pragma unroll
    for (int mi = 0; mi < 4; ++mi)
      a[mi] = *(const bf16x8*)(We1T + (size_t)(w * 64 + 16 * mi + r) * 512 + koff + k0 + q * 8);
#pragma unroll
    for (int ni = 0; ni < 4; ++ni) {
      int m = m0 + 16 * ni + r; if (m > N_NODES - 1) m = N_NODES - 1;
      b[ni] = *(const bf16x8*)(Hb + (size_t)m * 256 + k0 + q * 8);
    }
#pragma unroll
    for (int mi = 0; mi < 4; ++mi)
#pragma unroll
      for (int ni = 0; ni < 4; ++ni)
        acc[mi][ni] = __builtin_amdgcn_mfma_f32_16x16x32_bf16(a[mi], b[ni], acc[mi][ni], 0, 0, 0);
  }
#pragma unroll
  for (int mi = 0; mi < 4; ++mi) {
    int ch = w * 64 + 16 * mi + 4 * q;
    float4 bv = addb ? *(const float4*)(be1 + ch) : (float4){0.f, 0.f, 0.f, 0.f};
#pragma unroll
    for (int ni = 0; ni < 4; ++ni) {
      int m = m0 + 16 * ni + r;
      if (m < N_NODES) {
        uint2 o;
        o.x = pk_bf16(acc[mi][ni][0] + bv.x, acc[mi][ni][1] + bv.y);
        o.y = pk_bf16(acc[mi][ni][2] + bv.z, acc[mi][ni][3] + bv.w);
        *(uint2*)(OUT + (size_t)m * 256 + ch) = o;
      }
    }
  }
}

// ---- edge kernel: 64 sorted edges/block, transposed GEMMs, run-based aggregation
__global__ __launch_bounds__(256, 4) void edge_kernel(
    const float* __restrict__ coord, const int* __restrict__ rs, const int* __restrict__ cs,
    const float* __restrict__ We1,
    const float* __restrict__ be2, const float* __restrict__ bc1,
    const float* __restrict__ Wc2, const float* __restrict__ bc2,
    const bf16* __restrict__ P, const bf16* __restrict__ Q,
    const bf16* __restrict__ We2T, const bf16* __restrict__ Wc1T,
    float* __restrict__ agg_h, float* __restrict__ agg_c) {
  __shared__ __align__(16) bf16 buf[64 * KPAD];
  __shared__ int s_row[64], s_col[64];
  __shared__ float s_rad[64], s_cd[64][3], s_part[64][4], s_scal[64];
  __shared__ int s_rs[65];
  __shared__ int s_nrun;

  int tid = threadIdx.x;
  int e0 = blockIdx.x * 64;
  int w = tid >> 6, lane = tid & 63, r = lane & 15, q = lane >> 4;

  if (tid < 64) {
    int e = e0 + tid;
    int ri = rs[e], ci = cs[e];
    s_row[tid] = ri; s_col[tid] = ci;
    float dx = coord[3 * ri + 0] - coord[3 * ci + 0];
    float dy = coord[3 * ri + 1] - coord[3 * ci + 1];
    float dz = coord[3 * ri + 2] - coord[3 * ci + 2];
    s_cd[tid][0] = dx; s_cd[tid][1] = dy; s_cd[tid][2] = dz;
    s_rad[tid] = dx * dx + dy * dy + dz * dz;
  }
  __syncthreads();

  // wave 0: run boundaries of sorted rows (avg 2-3 runs/block)
  if (tid < 64) {
    bool bnd = (tid == 0) || (s_row[tid] != s_row[tid - 1]);
    unsigned long long m = __ballot(bnd);
    int rank = __popcll(m & ((1ull << tid) - 1ull));
    if (bnd) s_rs[rank] = tid;
    if (tid == 0) { int R = __popcll(m); s_nrun = R; s_rs[R] = 64; }
  }

  // e1 = silu(P[row] + Q[col] + radial*We1[512]) -> buf (be1 pre-folded into P)
  {
    int off = (tid & 31) * 8;
    int esub = tid >> 5;
    float4 wa = *(const float4*)(We1 + 512 * 256 + off);
    float4 wb = *(const float4*)(We1 + 512 * 256 + off + 4);
#pragma unroll
    for (int p = 0; p < 8; ++p) {
      int e = p * 8 + esub;
      int ri = s_row[e], ci = s_col[e];
      bf16x8 pv = *(const bf16x8*)(P + (size_t)ri * 256 + off);
      bf16x8 qv = *(const bf16x8*)(Q + (size_t)ci * 256 + off);
      float rad = s_rad[e];
      float f0 = silu_f((float)pv[0] + (float)qv[0] + rad * wa.x);
      float f1 = silu_f((float)pv[1] + (float)qv[1] + rad * wa.y);
      float f2 = silu_f((float)pv[2] + (float)qv[2] + rad * wa.z);
      float f3 = silu_f((float)pv[3] + (float)qv[3] + rad * wa.w);
      float f4 = silu_f((float)pv[4] + (float)qv[4] + rad * wb.x);
      float f5 = silu_f((float)pv[5] + (float)qv[5] + rad * wb.y);
      float f6 = silu_f((float)pv[6] + (float)qv[6] + rad * wb.z);
      float f7 = silu_f((float)pv[7] + (float)qv[7] + rad * wb.w);
      uint4 o;
      o.x = pk_bf16(f0, f1); o.y = pk_bf16(f2, f3);
      o.z = pk_bf16(f4, f5); o.w = pk_bf16(f6, f7);
      *(uint4*)(buf + e * KPAD + off) = o;
    }
  }
  __syncthreads();

  // GEMM1-T: edge_feat^? : acc rows = We2 out-channels, cols = edges
  {
    f32x4 acc[4][4];
#pragma unroll
    for (int mi = 0; mi < 4; ++mi)
#pragma unroll
      for (int ni = 0; ni < 4; ++ni) acc[mi][ni] = (f32x4){0.f, 0.f, 0.f, 0.f};
    mfmaT_k256(We2T, 256, 0, buf, w, r, q, acc);
    __syncthreads();   // all reads of e1 done before overwrite
#pragma unroll
    for (int mi = 0; mi < 4; ++mi) {
      int ch = w * 64 + 16 * mi + 4 * q;
      float4 bv = *(const float4*)(be2 + ch);
#pragma unroll
      for (int ni = 0; ni < 4; ++ni) {
        int edge = 16 * ni + r;
        float f0 = silu_f(acc[mi][ni][0] + bv.x);
        float f1 = silu_f(acc[mi][ni][1] + bv.y);
        float f2 = silu_f(acc[mi][ni][2] + bv.z);
        float f3 = silu_f(acc[mi][ni][3] + bv.w);
        uint2 o; o.x = pk_bf16(f0, f1); o.y = pk_bf16(f2, f3);
        *(uint2*)(buf + edge * KPAD + ch) = o;  // buf[edge][ch], b64 write
      }
    }
  }
  __syncthreads();

  // GEMM2-T k-loop (reads edge_feat) ...
  f32x4 acc2[4][4];
#pragma unroll
  for (int mi = 0; mi < 4; ++mi)
#pragma unroll
    for (int ni = 0; ni < 4; ++ni) acc2[mi][ni] = (f32x4){0.f, 0.f, 0.f, 0.f};
  mfmaT_k256(Wc1T, 256, 0, buf, w, r, q, acc2);

  // ... interleaved with run-based agg_h column sums (also reads edge_feat)
  {
    int R = s_nrun;
    for (int rr = 0; rr < R; ++rr) {
      int st = s_rs[rr], en = s_rs[rr + 1];
      float s = 0.f;
      for (int e = st; e < en; ++e) s += (float)buf[e * KPAD + tid];
      atomicAdd(&agg_h[(size_t)s_row[st] * 256 + tid], s);
    }
  }
  __syncthreads();   // all reads of edge_feat done before overwrite

  // GEMM2 epilogue: c1 -> buf[edge][ch]
#pragma unroll
  for (int mi = 0; mi < 4; ++mi) {
    int ch = w * 64 + 16 * mi + 4 * q;
    float4 bv = *(const float4*)(bc1 + ch);
#pragma unroll
    for (int ni = 0; ni < 4; ++ni) {
      int edge = 16 * ni + r;
      float f0 = silu_f(acc2[mi][ni][0] + bv.x);
      float f1 = silu_f(acc2[mi][ni][1] + bv.y);
      float f2 = silu_f(acc2[mi][ni][2] + bv.z);
      float f3 = silu_f(acc2[mi][ni][3] + bv.w);
      uint2 o; o.x = pk_bf16(f0, f1); o.y = pk_bf16(f2, f3);
      *(uint2*)(buf + edge * KPAD + ch) = o;
    }
  }
  __syncthreads();

  // scalar = c1 @ Wc2 + bc2
  {
    int e = tid >> 2, p = tid & 3;
    float s = 0.f;
#pragma unroll
    for (int kk = 0; kk < 64; kk += 8) {
      bf16x8 v = *(const bf16x8*)(buf + e * KPAD + p * 64 + kk);
      float4 w0 = *(const float4*)(Wc2 + p * 64 + kk);
      float4 w1 = *(const float4*)(Wc2 + p * 64 + kk + 4);
      s += (float)v[0] * w0.x + (float)v[1] * w0.y + (float)v[2] * w0.z + (float)v[3] * w0.w
         + (float)v[4] * w1.x + (float)v[5] * w1.y + (float)v[6] * w1.z + (float)v[7] * w1.w;
    }
    s_part[e][p] = s;
  }
  __syncthreads();
  if (tid < 64)
    s_scal[tid] = s_part[tid][0] + s_part[tid][1] + s_part[tid][2] + s_part[tid][3] + bc2[0];
  __syncthreads();

  // coord aggregation: run-based, one lane per xyz component
  if (tid < 3) {
    int R = s_nrun;
    for (int rr = 0; rr < R; ++rr) {
      int st = s_rs[rr], en = s_rs[rr + 1];
      float s = 0.f;
      for (int e = st; e < en; ++e) s += s_cd[e][tid] * s_scal[e];
      atomicAdd(&agg_c[3 * s_row[st] + tid], s);
    }
  }
}

// ---- node kernel (fused post): coord_out + agg->bf16 inline + 2-layer node MLP
__global__ __launch_bounds__(256, 2) void node_kernel(
    const bf16* __restrict__ Hb, const float* __restrict__ agg_h,
    const int* __restrict__ hist, const float* __restrict__ coord, const float* __restrict__ agg_c,
    const bf16* __restrict__ Wn1T, const bf16* __restrict__ Wn2T,
    const float* __restrict__ bn1, const float* __restrict__ bn2,
    float* __restrict__ h_out, float* __restrict__ coord_out) {
  __shared__ __align__(16) bf16 buf[64 * KPAD];
  int tid = threadIdx.x, w = tid >> 6, lane = tid & 63, r = lane & 15, q = lane >> 4;
  int m0 = blockIdx.x * 64;

  // coord_out
  if (tid < 64) {
    int m = m0 + tid;
    if (m < N_NODES) {
      float c = (float)hist[m]; if (c < 1.f) c = 1.f;
      coord_out[3 * m + 0] = coord[3 * m + 0] + agg_c[3 * m + 0] / c;
      coord_out[3 * m + 1] = coord[3 * m + 1] + agg_c[3 * m + 1] / c;
      coord_out[3 * m + 2] = coord[3 * m + 2] + agg_c[3 * m + 2] / c;
    }
  }

  // layer1: rows = hidden channels, cols = nodes
  f32x4 acc[4][4];
#pragma unroll
  for (int mi = 0; mi < 4; ++mi)
#pragma unroll
    for (int ni = 0; ni < 4; ++ni) acc[mi][ni] = (f32x4){0.f, 0.f, 0.f, 0.f};
  // part A: h (k 0..255), B from Hb global
  for (int k0 = 0; k0 < 256; k0 += 32) {
    bf16x8 a[4], b[4];
#pragma unroll
    for (int mi = 0; mi < 4; ++mi)
      a[mi] = *(const bf16x8*)(Wn1T + (size_t)(w * 64 + 16 * mi + r) * 512 + k0 + q * 8);
#pragma unroll
    for (int ni = 0; ni < 4; ++ni) {
      int m = m0 + 16 * ni + r; if (m > N_NODES - 1) m = N_NODES - 1;
      b[ni] = *(const bf16x8*)(Hb + (size_t)m * 256 + k0 + q * 8);
    }
#pragma unroll
    for (int mi = 0; mi < 4; ++mi)
#pragma unroll
      for (int ni = 0; ni < 4; ++ni)
        acc[mi][ni] = __builtin_amdgcn_mfma_f32_16x16x32_bf16(a[mi], b[ni], acc[mi][ni], 0, 0, 0);
  }
  // part B: agg_h f32 -> bf16 on the fly (k 256..511)
  for (int k0 = 0; k0 < 256; k0 += 32) {
    bf16x8 a[4], b[4];
#pragma unroll
    for (int mi = 0; mi < 4; ++mi)
      a[mi] = *(const bf16x8*)(Wn1T + (size_t)(w * 64 + 16 * mi + r) * 512 + 256 + k0 + q * 8);
#pragma unroll
    for (int ni = 0; ni < 4; ++ni) {
      int m = m0 + 16 * ni + r; if (m > N_NODES - 1) m = N_NODES - 1;
      const float* ap = agg_h + (size_t)m * 256 + k0 + q * 8;
      float4 u = *(const float4*)ap;
      float4 v = *(const float4*)(ap + 4);
      uint4 o;
      o.x = pk_bf16(u.x, u.y); o.y = pk_bf16(u.z, u.w);
      o.z = pk_bf16(v.x, v.y); o.w = pk_bf16(v.z, v.w);
      b[ni] = *(const bf16x8*)&o;
    }
#pragma unroll
    for (int mi = 0; mi < 4; ++mi)
#pragma unroll
      for (int ni = 0; ni < 4; ++ni)
        acc[mi][ni] = __builtin_amdgcn_mfma_f32_16x16x32_bf16(a[mi], b[ni], acc[mi][ni], 0, 0, 0);
  }
  __syncthreads();
  // epilogue -> buf[node_local][hidden], b64 writes
#pragma unroll
  for (int mi = 0; mi < 4; ++mi) {
    int ch = w * 64 + 16 * mi + 4 * q;
    float4 bv = *(const float4*)(bn1 + ch);
#pragma unroll
    for (int ni = 0; ni < 4; ++ni) {
      int lm = 16 * ni + r;
      float f0 = silu_f(acc[mi][ni][0] + bv.x);
      float f1 = silu_f(acc[mi][ni][1] + bv.y);
      float f2 = silu_f(acc[mi][ni][2] + bv.z);
      float f3 = silu_f(acc[mi][ni][3] + bv.w);
      uint2 o; o.x = pk_bf16(f0, f1); o.y = pk_bf16(f2, f3);
      *(uint2*)(buf + lm * KPAD + ch) = o;
    }
  }
  __syncthreads();
  // layer2 -> h_out (float4 stores)
  f32x4 acc2[4][4];
#pragma unroll
  for (int mi = 0; mi < 4; ++mi)
#pragma unroll
    for (int ni = 0; ni < 4; ++ni) acc2[mi][ni] = (f32x4){0.f, 0.f, 0.f, 0.f};
  mfmaT_k256(Wn2T, 256, 0, buf, w, r, q, acc2);
#pragma unroll
  for (int mi = 0; mi < 4; ++mi) {
    int ch = w * 64 + 16 * mi + 4 * q;
    float4 bv = *(const float4*)(bn2 + ch);
#pragma unroll
    for (int ni = 0; ni < 4; ++ni) {
      int m = m0 + 16 * ni + r;
      if (m < N_NODES) {
        float4 o;
        o.x = acc2[mi][ni][0] + bv.x;
        o.y = acc2[mi][ni][1] + bv.y;
        o.z = acc2[mi][ni][2] + bv.z;
        o.w = acc2[mi][ni][3] + bv.w;
        *(float4*)(h_out + (size_t)m * 256 + ch) = o;
      }
    }
  }
}

extern "C" void kernel_launch(void* const* d_in, const int* in_sizes, int n_in,
                              void* d_out, int out_size, void* d_ws, size_t ws_size,
                              hipStream_t stream) {
  const float* h     = (const float*)d_in[0];
  const float* coord = (const float*)d_in[1];
  const int*   eidx  = (const int*)d_in[2];
  const float* We1 = (const float*)d_in[3];
  const float* be1 = (const float*)d_in[4];
  const float* We2 = (const float*)d_in[5];
  const float* be2 = (const float*)d_in[6];
  const float* Wn1 = (const float*)d_in[7];
  const float* bn1 = (const float*)d_in[8];
  const float* Wn2 = (const float*)d_in[9];
  const float* bn2 = (const float*)d_in[10];
  const float* Wc1 = (const float*)d_in[11];
  const float* bc1 = (const float*)d_in[12];
  const float* Wc2 = (const float*)d_in[13];
  const float* bc2 = (const float*)d_in[14];

  char* ws = (char*)d_ws;
  float* agg_h = (float*)(ws + 0);          // 10,240,000
  float* agg_c = (float*)(ws + 10240000);   //    120,000
  int*   hist  = (int*)  (ws + 10360000);   //     40,000
  int*   base  = (int*)  (ws + 10400000);   //     40,000
  int*   cursor= (int*)  (ws + 10440000);   //     40,000
  int*   rs    = (int*)  (ws + 10480000);   //  1,280,000
  int*   cs    = (int*)  (ws + 11760000);   //  1,280,000
  bf16* Hb   = (bf16*)(ws + 13040000);      //  5,120,000
  bf16* P    = (bf16*)(ws + 18160000);      //  5,120,000
  bf16* Q    = (bf16*)(ws + 23280000);      //  5,120,000
  bf16* We1T = (bf16*)(ws + 28400000);      //    262,144
  bf16* Wn1T = (bf16*)(ws + 28662144);      //    262,144
  bf16* We2T = (bf16*)(ws + 28924288);      //    131,072
  bf16* Wn2T = (bf16*)(ws + 29055360);      //    131,072
  bf16* Wc1T = (bf16*)(ws + 29186432);      //    131,072

  float* h_out = (float*)d_out;
  float* coord_out = h_out + (size_t)N_NODES * 256;

  hipMemsetAsync(ws, 0, 10400000, stream);  // agg_h + agg_c + hist
  prep_kernel<<<13042, 256, 0, stream>>>(h, We1, We2, Wn1, Wn2, Wc1, eidx,
                                         Hb, We1T, Wn1T, We2T, Wn2T, Wc1T, hist);
  scan_kernel<<<1, 256, 0, stream>>>(hist, base, cursor);
  scatter_kernel<<<1250, 256, 0, stream>>>(eidx, cursor, rs, cs);
  gemm_pq<<<dim3(157, 2), 256, 0, stream>>>(Hb, We1T, be1, P, Q);
  edge_kernel<<<5000, 256, 0, stream>>>(coord, rs, cs, We1, be2, bc1, Wc2, bc2,
                                        P, Q, We2T, Wc1T, agg_h, agg_c);
  node_kernel<<<157, 256, 0, stream>>>(Hb, agg_h, hist, coord, agg_c,
                                       Wn1T, Wn2T, bn1, bn2, h_out, coord_out);
}